// Round 1
// baseline (1296.364 us; speedup 1.0000x reference)
//
#include <hip/hip_runtime.h>
#include <hip/hip_bf16.h>

constexpr int SEQ = 2048;
constexpr int EMB = 4096;
constexpr int NH  = 32;
constexpr int HD  = 128;
constexpr int HALF = 64;

typedef __bf16 bf16x8 __attribute__((ext_vector_type(8)));
typedef float  f32x4  __attribute__((ext_vector_type(4)));
typedef float  f32x4v __attribute__((ext_vector_type(4)));
using u16 = unsigned short;
typedef u16 ushort8 __attribute__((ext_vector_type(8)));

__device__ inline float bf2f(u16 u) {
  union { unsigned int i; float f; } v; v.i = ((unsigned int)u) << 16; return v.f;
}
__device__ inline u16 f2bf(float f) {
  union { __bf16 b; u16 u; } v; v.b = (__bf16)f; return v.u;
}

// ---------------- fp32 -> bf16 conversion (vectorized) ----------------
__global__ void k_f32_to_bf16(const float* __restrict__ in, u16* __restrict__ out, int n) {
  int i = (blockIdx.x * blockDim.x + threadIdx.x) * 8;
  if (i >= n) return;
  f32x4v a = *(const f32x4v*)(in + i);
  f32x4v b = *(const f32x4v*)(in + i + 4);
  ushort8 o;
  o[0] = f2bf(a[0]); o[1] = f2bf(a[1]); o[2] = f2bf(a[2]); o[3] = f2bf(a[3]);
  o[4] = f2bf(b[0]); o[5] = f2bf(b[1]); o[6] = f2bf(b[2]); o[7] = f2bf(b[3]);
  *(ushort8*)(out + i) = o;
}

// ---------------- RoPE cos/sin table (fp64 for exactness) ----------------
__global__ void k_rope_table(const int* __restrict__ pos, float* __restrict__ tab) {
  int idx = blockIdx.x * blockDim.x + threadIdx.x;
  if (idx >= SEQ * HALF) return;
  int s = idx >> 6, d = idx & 63;
  double invf = pow(10000.0, -(double)d / 64.0);
  double ang = (double)pos[s] * invf;
  tab[idx * 2]     = (float)cos(ang);
  tab[idx * 2 + 1] = (float)sin(ang);
}

// ---------------- RoPE apply (in-place on bf16, optional 1/sqrt(D) fold) ----------------
__global__ void k_rope(u16* __restrict__ X, const float* __restrict__ tab, float scale) {
  int idx = blockIdx.x * blockDim.x + threadIdx.x;   // SEQ*NH*HALF
  if (idx >= SEQ * NH * HALF) return;
  int d = idx & 63;
  int h = (idx >> 6) & 31;
  int s = idx >> 11;
  u16* p = X + (size_t)s * EMB + h * HD + d;
  float x1 = bf2f(p[0]), x2 = bf2f(p[HALF]);
  float c  = tab[(s * HALF + d) * 2];
  float sn = tab[(s * HALF + d) * 2 + 1];
  p[0]    = f2bf((x1 * c - x2 * sn) * scale);
  p[HALF] = f2bf((x2 * c + x1 * sn) * scale);
}

// ---------------- bf16 MFMA GEMM:  C[M][N] = A[M][K] * W[N][K]^T + bias ----------------
// 128x128 tile, BK=32, 4 waves (2x2), 4x4 16x16x32 fragments per wave.
constexpr int BM = 128, BN = 128, BK = 32, LDT = 40;  // LDT: padded LDS row stride (halves)

__global__ __launch_bounds__(256) void k_gemm_bf16(
    const u16* __restrict__ A, const u16* __restrict__ W, const float* __restrict__ bias,
    void* __restrict__ Cout, int M, int N, int K, int out_f32)
{
  __shared__ alignas(16) u16 As[BM * LDT];
  __shared__ alignas(16) u16 Bs[BN * LDT];
  int tid = threadIdx.x;
  int lane = tid & 63, wid = tid >> 6;
  int wm = wid >> 1, wn = wid & 1;
  int l15 = lane & 15, lhi = lane >> 4;
  int m0 = blockIdx.y * BM, n0 = blockIdx.x * BN;

  f32x4 acc[4][4] = {};

  for (int k0 = 0; k0 < K; k0 += BK) {
    __syncthreads();
    for (int c = tid; c < 512; c += 256) {
      int row = c >> 2, col = (c & 3) * 8;
      *(ushort8*)&As[row * LDT + col] = *(const ushort8*)&A[(size_t)(m0 + row) * K + k0 + col];
    }
    for (int c = tid; c < 512; c += 256) {
      int row = c >> 2, col = (c & 3) * 8;
      *(ushort8*)&Bs[row * LDT + col] = *(const ushort8*)&W[(size_t)(n0 + row) * K + k0 + col];
    }
    __syncthreads();
    bf16x8 af[4], bfr[4];
    for (int a = 0; a < 4; a++)
      af[a] = *(const bf16x8*)&As[(wm * 64 + a * 16 + l15) * LDT + lhi * 8];
    for (int b = 0; b < 4; b++)
      bfr[b] = *(const bf16x8*)&Bs[(wn * 64 + b * 16 + l15) * LDT + lhi * 8];
    for (int a = 0; a < 4; a++)
      for (int b = 0; b < 4; b++)
        acc[a][b] = __builtin_amdgcn_mfma_f32_16x16x32_bf16(af[a], bfr[b], acc[a][b], 0, 0, 0);
  }

  for (int a = 0; a < 4; a++) {
    int m = m0 + wm * 64 + a * 16 + lhi * 4;
    for (int b = 0; b < 4; b++) {
      int n = n0 + wn * 64 + b * 16 + l15;
      float bs = bias[n];
      for (int r = 0; r < 4; r++) {
        float v = acc[a][b][r] + bs;
        if (out_f32) ((float*)Cout)[(size_t)(m + r) * N + n] = v;
        else         ((u16*)Cout)[(size_t)(m + r) * N + n] = f2bf(v);
      }
    }
  }
}

// ---------------- Flash attention (causal), bf16 MFMA, fp32 softmax ----------------
// Q-block 64 rows (4 waves x 16), KV-block 64. Q pre-scaled by 1/sqrt(D).
constexpr int QB = 64, KVB = 64;
constexpr int LKS = 136;  // K tile row stride (halves), [64][128]+pad
constexpr int LVT = 72;   // V^T tile row stride, [128][64]+pad
constexpr int LP  = 72;   // P tile row stride, per-wave [16][64]+pad

__global__ __launch_bounds__(256) void k_flash(
    const u16* __restrict__ Q, const u16* __restrict__ K, const u16* __restrict__ V,
    u16* __restrict__ ctx)
{
  __shared__ alignas(16) u16 Ks[KVB * LKS];
  __shared__ alignas(16) u16 Vt[HD * LVT];
  __shared__ alignas(16) u16 Pl[4][16 * LP];

  int tid = threadIdx.x, lane = tid & 63, wid = tid >> 6;
  int l15 = lane & 15, lhi = lane >> 4;
  int q0 = blockIdx.x * QB;
  int h  = blockIdx.y;
  int qw = q0 + wid * 16;

  bf16x8 qf[4];
  for (int kc = 0; kc < 4; kc++)
    qf[kc] = *(const bf16x8*)&Q[(size_t)(qw + l15) * EMB + h * HD + kc * 32 + lhi * 8];

  f32x4 O[8] = {};
  float mrow[4], lrow[4];
  for (int r = 0; r < 4; r++) { mrow[r] = -3.0e38f; lrow[r] = 0.f; }

  int ntiles = blockIdx.x + 1;
  for (int t = 0; t < ntiles; t++) {
    int kv0 = t * KVB;
    __syncthreads();
    for (int c = tid; c < 1024; c += 256) {
      int row = c >> 4, col = (c & 15) * 8;
      *(ushort8*)&Ks[row * LKS + col] =
          *(const ushort8*)&K[(size_t)(kv0 + row) * EMB + h * HD + col];
    }
    for (int c = tid; c < 1024; c += 256) {
      int row = c >> 4, col = (c & 15) * 8;
      ushort8 v = *(const ushort8*)&V[(size_t)(kv0 + row) * EMB + h * HD + col];
      for (int j = 0; j < 8; j++) Vt[(col + j) * LVT + row] = v[j];
    }
    __syncthreads();

    float p[4][4];
    bool need_mask = (kv0 + KVB - 1) > qw;
    for (int c = 0; c < 4; c++) {
      f32x4 s = {};
      for (int kc = 0; kc < 4; kc++) {
        bf16x8 kf = *(const bf16x8*)&Ks[(c * 16 + l15) * LKS + kc * 32 + lhi * 8];
        s = __builtin_amdgcn_mfma_f32_16x16x32_bf16(qf[kc], kf, s, 0, 0, 0);
      }
      for (int r = 0; r < 4; r++) {
        float sv = s[r];
        if (need_mask) {
          int qg = qw + lhi * 4 + r;
          int kg = kv0 + c * 16 + l15;
          if (kg > qg) sv = -3.0e38f;
        }
        p[c][r] = sv;
      }
    }
    // online softmax
    float fscale[4], rsum[4];
    for (int r = 0; r < 4; r++) {
      float m = fmaxf(fmaxf(p[0][r], p[1][r]), fmaxf(p[2][r], p[3][r]));
      for (int x = 1; x < 16; x <<= 1) m = fmaxf(m, __shfl_xor(m, x, 64));
      float mnew = fmaxf(mrow[r], m);
      fscale[r] = expf(mrow[r] - mnew);
      mrow[r] = mnew;
    }
    for (int c = 0; c < 4; c++)
      for (int r = 0; r < 4; r++)
        p[c][r] = expf(p[c][r] - mrow[r]);
    for (int r = 0; r < 4; r++) {
      float s = p[0][r] + p[1][r] + p[2][r] + p[3][r];
      for (int x = 1; x < 16; x <<= 1) s += __shfl_xor(s, x, 64);
      rsum[r] = s;
      lrow[r] = lrow[r] * fscale[r] + rsum[r];
    }
    for (int d = 0; d < 8; d++)
      for (int r = 0; r < 4; r++)
        O[d][r] *= fscale[r];
    for (int c = 0; c < 4; c++)
      for (int r = 0; r < 4; r++)
        Pl[wid][(lhi * 4 + r) * LP + c * 16 + l15] = f2bf(p[c][r]);
    __syncthreads();
    for (int ks = 0; ks < 2; ks++) {
      bf16x8 pf = *(const bf16x8*)&Pl[wid][l15 * LP + ks * 32 + lhi * 8];
      for (int ds = 0; ds < 8; ds++) {
        bf16x8 vf = *(const bf16x8*)&Vt[(ds * 16 + l15) * LVT + ks * 32 + lhi * 8];
        O[ds] = __builtin_amdgcn_mfma_f32_16x16x32_bf16(pf, vf, O[ds], 0, 0, 0);
      }
    }
  }

  for (int r = 0; r < 4; r++) {
    float inv = 1.f / lrow[r];
    int qg = qw + lhi * 4 + r;
    for (int ds = 0; ds < 8; ds++)
      ctx[(size_t)qg * EMB + h * HD + ds * 16 + l15] = f2bf(O[ds][r] * inv);
  }
}

// ---------------- launch ----------------
extern "C" void kernel_launch(void* const* d_in, const int* in_sizes, int n_in,
                              void* d_out, int out_size, void* d_ws, size_t ws_size,
                              hipStream_t stream) {
  const float* hs = (const float*)d_in[0];
  const float* wq = (const float*)d_in[1];
  const float* bq = (const float*)d_in[2];
  const float* wk = (const float*)d_in[3];
  const float* bk = (const float*)d_in[4];
  const float* wv = (const float*)d_in[5];
  const float* bv = (const float*)d_in[6];
  const float* wo = (const float*)d_in[7];
  const float* bo = (const float*)d_in[8];
  const int*  pos = (const int*)d_in[9];

  char* ws = (char*)d_ws;
  size_t off = 0;
  auto alloc = [&](size_t b) { size_t o = off; off += (b + 255) & ~(size_t)255; return o; };
  u16*  hsb  = (u16*)(ws + alloc((size_t)SEQ * EMB * 2));
  u16*  wb   = (u16*)(ws + alloc((size_t)EMB * EMB * 2));   // reused for wq/wk/wv/wo
  u16*  Qb   = (u16*)(ws + alloc((size_t)SEQ * EMB * 2));
  u16*  Kb   = (u16*)(ws + alloc((size_t)SEQ * EMB * 2));
  u16*  Vb   = (u16*)(ws + alloc((size_t)SEQ * EMB * 2));
  u16*  ctxb = (u16*)(ws + alloc((size_t)SEQ * EMB * 2));
  float* tab = (float*)(ws + alloc((size_t)SEQ * HALF * 2 * 4));

  const float qscale = 1.0f / 11.313708498984761f;  // 1/sqrt(128)

  hipLaunchKernelGGL(k_f32_to_bf16, dim3(SEQ * EMB / 2048), dim3(256), 0, stream, hs, hsb, SEQ * EMB);
  hipLaunchKernelGGL(k_rope_table, dim3(SEQ * HALF / 256), dim3(256), 0, stream, pos, tab);

  dim3 gg(EMB / BN, SEQ / BM);
  dim3 gb(256);

  // Q
  hipLaunchKernelGGL(k_f32_to_bf16, dim3(EMB * EMB / 2048), dim3(256), 0, stream, wq, wb, EMB * EMB);
  hipLaunchKernelGGL(k_gemm_bf16, gg, gb, 0, stream, hsb, wb, bq, (void*)Qb, SEQ, EMB, EMB, 0);
  // K
  hipLaunchKernelGGL(k_f32_to_bf16, dim3(EMB * EMB / 2048), dim3(256), 0, stream, wk, wb, EMB * EMB);
  hipLaunchKernelGGL(k_gemm_bf16, gg, gb, 0, stream, hsb, wb, bk, (void*)Kb, SEQ, EMB, EMB, 0);
  // RoPE on Q (with 1/sqrt(D) folded) and K
  hipLaunchKernelGGL(k_rope, dim3(SEQ * NH * HALF / 256), dim3(256), 0, stream, Qb, tab, qscale);
  hipLaunchKernelGGL(k_rope, dim3(SEQ * NH * HALF / 256), dim3(256), 0, stream, Kb, tab, 1.0f);
  // V
  hipLaunchKernelGGL(k_f32_to_bf16, dim3(EMB * EMB / 2048), dim3(256), 0, stream, wv, wb, EMB * EMB);
  hipLaunchKernelGGL(k_gemm_bf16, gg, gb, 0, stream, hsb, wb, bv, (void*)Vb, SEQ, EMB, EMB, 0);
  // attention
  hipLaunchKernelGGL(k_flash, dim3(SEQ / QB, NH), gb, 0, stream, Qb, Kb, Vb, ctxb);
  // output projection (fp32 out)
  hipLaunchKernelGGL(k_f32_to_bf16, dim3(EMB * EMB / 2048), dim3(256), 0, stream, wo, wb, EMB * EMB);
  hipLaunchKernelGGL(k_gemm_bf16, gg, gb, 0, stream, ctxb, wb, bo, d_out, SEQ, EMB, EMB, 1);
}

// Round 2
// 712.001 us; speedup vs baseline: 1.8207x; 1.8207x over previous
//
#include <hip/hip_runtime.h>
#include <hip/hip_bf16.h>

constexpr int SEQ = 2048;
constexpr int EMB = 4096;
constexpr int NH  = 32;
constexpr int HD  = 128;
constexpr int HALF = 64;

typedef __bf16 bf16x8 __attribute__((ext_vector_type(8)));
typedef float  f32x4  __attribute__((ext_vector_type(4)));
using u16 = unsigned short;
typedef u16 ushort8 __attribute__((ext_vector_type(8)));

__device__ inline float bf2f(u16 u) {
  union { unsigned int i; float f; } v; v.i = ((unsigned int)u) << 16; return v.f;
}
__device__ inline u16 f2bf(float f) {
  union { __bf16 b; u16 u; } v; v.b = (__bf16)f; return v.u;
}

// ---------------- fp32 -> bf16 conversion (vectorized) ----------------
__global__ void k_f32_to_bf16(const float* __restrict__ in, u16* __restrict__ out, int n) {
  int i = (blockIdx.x * blockDim.x + threadIdx.x) * 8;
  if (i >= n) return;
  f32x4 a = *(const f32x4*)(in + i);
  f32x4 b = *(const f32x4*)(in + i + 4);
  ushort8 o;
  o[0] = f2bf(a[0]); o[1] = f2bf(a[1]); o[2] = f2bf(a[2]); o[3] = f2bf(a[3]);
  o[4] = f2bf(b[0]); o[5] = f2bf(b[1]); o[6] = f2bf(b[2]); o[7] = f2bf(b[3]);
  *(ushort8*)(out + i) = o;
}

// ---------------- RoPE cos/sin table (fp64 for exactness) ----------------
__global__ void k_rope_table(const int* __restrict__ pos, float* __restrict__ tab) {
  int idx = blockIdx.x * blockDim.x + threadIdx.x;
  if (idx >= SEQ * HALF) return;
  int s = idx >> 6, d = idx & 63;
  double invf = pow(10000.0, -(double)d / 64.0);
  double ang = (double)pos[s] * invf;
  tab[idx * 2]     = (float)cos(ang);
  tab[idx * 2 + 1] = (float)sin(ang);
}

// ---------------- RoPE apply (in-place on bf16, optional 1/sqrt(D) fold) ----------------
__global__ void k_rope(u16* __restrict__ X, const float* __restrict__ tab, float scale) {
  int idx = blockIdx.x * blockDim.x + threadIdx.x;   // SEQ*NH*HALF
  if (idx >= SEQ * NH * HALF) return;
  int d = idx & 63;
  int h = (idx >> 6) & 31;
  int s = idx >> 11;
  u16* p = X + (size_t)s * EMB + h * HD + d;
  float x1 = bf2f(p[0]), x2 = bf2f(p[HALF]);
  float c  = tab[(s * HALF + d) * 2];
  float sn = tab[(s * HALF + d) * 2 + 1];
  p[0]    = f2bf((x1 * c - x2 * sn) * scale);
  p[HALF] = f2bf((x2 * c + x1 * sn) * scale);
}

// ---------------- bf16 MFMA GEMM (m97 structure):  C = A[M][K] * W[N][K]^T + bias ----------------
// 128x128 tile, BK=32, 4 waves (2x2), linear LDS [128][32], global_load_lds width=16.
constexpr int BM = 128, BN = 128, BK = 32;

__global__ __launch_bounds__(256) void k_gemm_bf16(
    const u16* __restrict__ A, const u16* __restrict__ W, const float* __restrict__ bias,
    void* __restrict__ Cout, int M, int N, int K, int out_f32)
{
  __shared__ alignas(16) u16 As[BM * BK];
  __shared__ alignas(16) u16 Bs[BN * BK];
  int tid = threadIdx.x;
  int lane = tid & 63, wid = tid >> 6;
  int wm = wid >> 1, wn = wid & 1;
  int l15 = lane & 15, lhi = lane >> 4;

  // bijective XCD swizzle (nwg % 8 == 0 here: 32*16=512)
  int nwg = gridDim.x * gridDim.y;
  int lin = blockIdx.y * gridDim.x + blockIdx.x;
  int cpx = nwg >> 3;
  int swz = (lin & 7) * cpx + (lin >> 3);
  int bx = swz % gridDim.x, by = swz / gridDim.x;
  int m0 = by * BM, n0 = bx * BN;

  f32x4 acc[4][4] = {};

  int srow = (lane >> 2);          // 0..15 within chunk
  int scol = (lane & 3) * 8;       // 0,8,16,24

  for (int k0 = 0; k0 < K; k0 += BK) {
    __syncthreads();   // previous tile fully consumed
#pragma unroll
    for (int i = 0; i < 2; i++) {
      int chunk = wid * 2 + i;               // 0..7
      int row = chunk * 16 + srow;
      __builtin_amdgcn_global_load_lds(
          (const __attribute__((address_space(1))) void*)(A + (size_t)(m0 + row) * K + k0 + scol),
          (__attribute__((address_space(3))) void*)(As + chunk * 512), 16, 0, 0);
      __builtin_amdgcn_global_load_lds(
          (const __attribute__((address_space(1))) void*)(W + (size_t)(n0 + row) * K + k0 + scol),
          (__attribute__((address_space(3))) void*)(Bs + chunk * 512), 16, 0, 0);
    }
    __syncthreads();   // vmcnt(0) drained before barrier -> data visible

    bf16x8 af[4], bfr[4];
#pragma unroll
    for (int a = 0; a < 4; a++)
      af[a] = *(const bf16x8*)&As[(wm * 64 + a * 16 + l15) * BK + lhi * 8];
#pragma unroll
    for (int b = 0; b < 4; b++)
      bfr[b] = *(const bf16x8*)&Bs[(wn * 64 + b * 16 + l15) * BK + lhi * 8];
#pragma unroll
    for (int a = 0; a < 4; a++)
#pragma unroll
      for (int b = 0; b < 4; b++)
        acc[a][b] = __builtin_amdgcn_mfma_f32_16x16x32_bf16(af[a], bfr[b], acc[a][b], 0, 0, 0);
  }

#pragma unroll
  for (int a = 0; a < 4; a++) {
    int m = m0 + wm * 64 + a * 16 + lhi * 4;
#pragma unroll
    for (int b = 0; b < 4; b++) {
      int n = n0 + wn * 64 + b * 16 + l15;
      float bs = bias[n];
#pragma unroll
      for (int r = 0; r < 4; r++) {
        float v = acc[a][b][r] + bs;
        if (out_f32) ((float*)Cout)[(size_t)(m + r) * N + n] = v;
        else         ((u16*)Cout)[(size_t)(m + r) * N + n] = f2bf(v);
      }
    }
  }
}

// ---------------- Flash attention (causal), bf16 MFMA, fp32 softmax ----------------
// Q-block 64 rows (4 waves x 16), KV-block 64.
// All LDS tiles use linear row stride + 16B-block rotation for bank-conflict freedom:
//   addr(r, c) = r*S + ((c>>3 + g(r)) & (S/8-1))*8 + (c&7)
// Ks: [64][128]  g(r)=r         (reads vary r by l15 -> blocks spread)
// Vt: [128][64]  g(d)=d+(d>>3)  (writes vary d by 8*l15; reads vary d by l15 -> both spread)
// Pl: [16][64]   g(q)=q+(q>>3)  (wave-private)
constexpr int QB = 64, KVB = 64;

__device__ inline int ks_off(int r, int cblk) { return r * 128 + (((cblk + r) & 15) << 3); }
__device__ inline int vt_off(int d, int kblk) { return d * 64 + (((kblk + d + (d >> 3)) & 7) << 3); }
__device__ inline int pl_off(int q, int kblk) { return q * 64 + (((kblk + q + (q >> 3)) & 7) << 3); }

__global__ __launch_bounds__(256) void k_flash(
    const u16* __restrict__ Q, const u16* __restrict__ K, const u16* __restrict__ V,
    u16* __restrict__ ctx)
{
  __shared__ alignas(16) u16 Ks[KVB * 128];
  __shared__ alignas(16) u16 Vt[HD * 64];
  __shared__ alignas(16) u16 Pl[4][16 * 64];

  int tid = threadIdx.x, lane = tid & 63, wid = tid >> 6;
  int l15 = lane & 15, lhi = lane >> 4;
  int qb = gridDim.x - 1 - blockIdx.x;   // heavy blocks first
  int q0 = qb * QB;
  int h  = blockIdx.y;
  int qw = q0 + wid * 16;

  bf16x8 qf[4];
#pragma unroll
  for (int kc = 0; kc < 4; kc++)
    qf[kc] = *(const bf16x8*)&Q[(size_t)(qw + l15) * EMB + h * HD + kc * 32 + lhi * 8];

  f32x4 O[8] = {};
  float mrow[4], lrow[4];
#pragma unroll
  for (int r = 0; r < 4; r++) { mrow[r] = -3.0e38f; lrow[r] = 0.f; }

  int ntiles = qb + 1;
  for (int t = 0; t < ntiles; t++) {
    int kv0 = t * KVB;
    __syncthreads();   // previous tile's Ks/Vt reads complete
#pragma unroll
    for (int it = 0; it < 4; it++) {
      int c = tid + it * 256;
      int row = c >> 4, cblk = c & 15;
      *(ushort8*)&Ks[ks_off(row, cblk)] =
          *(const ushort8*)&K[(size_t)(kv0 + row) * EMB + h * HD + cblk * 8];
    }
#pragma unroll
    for (int it = 0; it < 4; it++) {
      int c = tid + it * 256;
      int row = c >> 4, cblk = c & 15;
      ushort8 v = *(const ushort8*)&V[(size_t)(kv0 + row) * EMB + h * HD + cblk * 8];
      int kblk = row >> 3, klo = row & 7;
#pragma unroll
      for (int j = 0; j < 8; j++)
        Vt[vt_off(cblk * 8 + j, kblk) + klo] = v[j];
    }
    __syncthreads();

    float p[4][4];
    bool need_mask = (kv0 + KVB - 1) > qw;
#pragma unroll
    for (int c = 0; c < 4; c++) {
      f32x4 s = {};
#pragma unroll
      for (int kc = 0; kc < 4; kc++) {
        bf16x8 kf = *(const bf16x8*)&Ks[ks_off(c * 16 + l15, kc * 4 + lhi)];
        s = __builtin_amdgcn_mfma_f32_16x16x32_bf16(qf[kc], kf, s, 0, 0, 0);
      }
#pragma unroll
      for (int r = 0; r < 4; r++) {
        float sv = s[r];
        if (need_mask) {
          int qg = qw + lhi * 4 + r;
          int kg = kv0 + c * 16 + l15;
          if (kg > qg) sv = -3.0e38f;
        }
        p[c][r] = sv;
      }
    }
    // online softmax (rows live across 16 lanes of l15)
    float fscale[4];
#pragma unroll
    for (int r = 0; r < 4; r++) {
      float m = fmaxf(fmaxf(p[0][r], p[1][r]), fmaxf(p[2][r], p[3][r]));
#pragma unroll
      for (int x = 1; x < 16; x <<= 1) m = fmaxf(m, __shfl_xor(m, x, 64));
      float mnew = fmaxf(mrow[r], m);
      fscale[r] = __expf(mrow[r] - mnew);
      mrow[r] = mnew;
    }
#pragma unroll
    for (int c = 0; c < 4; c++)
#pragma unroll
      for (int r = 0; r < 4; r++)
        p[c][r] = __expf(p[c][r] - mrow[r]);
#pragma unroll
    for (int r = 0; r < 4; r++) {
      float s = p[0][r] + p[1][r] + p[2][r] + p[3][r];
#pragma unroll
      for (int x = 1; x < 16; x <<= 1) s += __shfl_xor(s, x, 64);
      lrow[r] = lrow[r] * fscale[r] + s;
    }
#pragma unroll
    for (int d = 0; d < 8; d++)
#pragma unroll
      for (int r = 0; r < 4; r++)
        O[d][r] *= fscale[r];
    // P -> wave-private LDS (no barrier needed; same wave reads it back)
#pragma unroll
    for (int c = 0; c < 4; c++) {
      int kblk = c * 2 + (l15 >> 3), klo = l15 & 7;
#pragma unroll
      for (int r = 0; r < 4; r++)
        Pl[wid][pl_off(lhi * 4 + r, kblk) + klo] = f2bf(p[c][r]);
    }
#pragma unroll
    for (int ks = 0; ks < 2; ks++) {
      bf16x8 pf = *(const bf16x8*)&Pl[wid][pl_off(l15, ks * 4 + lhi)];
#pragma unroll
      for (int ds = 0; ds < 8; ds++) {
        bf16x8 vf = *(const bf16x8*)&Vt[vt_off(ds * 16 + l15, ks * 4 + lhi)];
        O[ds] = __builtin_amdgcn_mfma_f32_16x16x32_bf16(pf, vf, O[ds], 0, 0, 0);
      }
    }
  }

#pragma unroll
  for (int r = 0; r < 4; r++) {
    float inv = 1.f / lrow[r];
    int qg = q0 + wid * 16 + lhi * 4 + r;
#pragma unroll
    for (int ds = 0; ds < 8; ds++)
      ctx[(size_t)qg * EMB + h * HD + ds * 16 + l15] = f2bf(O[ds][r] * inv);
  }
}

// ---------------- launch ----------------
extern "C" void kernel_launch(void* const* d_in, const int* in_sizes, int n_in,
                              void* d_out, int out_size, void* d_ws, size_t ws_size,
                              hipStream_t stream) {
  const float* hs = (const float*)d_in[0];
  const float* wq = (const float*)d_in[1];
  const float* bq = (const float*)d_in[2];
  const float* wk = (const float*)d_in[3];
  const float* bk = (const float*)d_in[4];
  const float* wv = (const float*)d_in[5];
  const float* bv = (const float*)d_in[6];
  const float* wo = (const float*)d_in[7];
  const float* bo = (const float*)d_in[8];
  const int*  pos = (const int*)d_in[9];

  char* ws = (char*)d_ws;
  size_t off = 0;
  auto alloc = [&](size_t b) { size_t o = off; off += (b + 255) & ~(size_t)255; return o; };
  u16*  hsb  = (u16*)(ws + alloc((size_t)SEQ * EMB * 2));
  u16*  wb   = (u16*)(ws + alloc((size_t)EMB * EMB * 2));   // reused for wq/wk/wv/wo
  u16*  Qb   = (u16*)(ws + alloc((size_t)SEQ * EMB * 2));
  u16*  Kb   = (u16*)(ws + alloc((size_t)SEQ * EMB * 2));
  u16*  Vb   = (u16*)(ws + alloc((size_t)SEQ * EMB * 2));
  u16*  ctxb = (u16*)(ws + alloc((size_t)SEQ * EMB * 2));
  float* tab = (float*)(ws + alloc((size_t)SEQ * HALF * 2 * 4));

  const float qscale = 1.0f / 11.313708498984761f;  // 1/sqrt(128)

  hipLaunchKernelGGL(k_f32_to_bf16, dim3(SEQ * EMB / 2048), dim3(256), 0, stream, hs, hsb, SEQ * EMB);
  hipLaunchKernelGGL(k_rope_table, dim3(SEQ * HALF / 256), dim3(256), 0, stream, pos, tab);

  dim3 gg(EMB / BN, SEQ / BM);
  dim3 gb(256);

  // Q
  hipLaunchKernelGGL(k_f32_to_bf16, dim3(EMB * EMB / 2048), dim3(256), 0, stream, wq, wb, EMB * EMB);
  hipLaunchKernelGGL(k_gemm_bf16, gg, gb, 0, stream, hsb, wb, bq, (void*)Qb, SEQ, EMB, EMB, 0);
  // K
  hipLaunchKernelGGL(k_f32_to_bf16, dim3(EMB * EMB / 2048), dim3(256), 0, stream, wk, wb, EMB * EMB);
  hipLaunchKernelGGL(k_gemm_bf16, gg, gb, 0, stream, hsb, wb, bk, (void*)Kb, SEQ, EMB, EMB, 0);
  // RoPE on Q (with 1/sqrt(D) folded) and K
  hipLaunchKernelGGL(k_rope, dim3(SEQ * NH * HALF / 256), dim3(256), 0, stream, Qb, tab, qscale);
  hipLaunchKernelGGL(k_rope, dim3(SEQ * NH * HALF / 256), dim3(256), 0, stream, Kb, tab, 1.0f);
  // V
  hipLaunchKernelGGL(k_f32_to_bf16, dim3(EMB * EMB / 2048), dim3(256), 0, stream, wv, wb, EMB * EMB);
  hipLaunchKernelGGL(k_gemm_bf16, gg, gb, 0, stream, hsb, wb, bv, (void*)Vb, SEQ, EMB, EMB, 0);
  // attention
  hipLaunchKernelGGL(k_flash, dim3(SEQ / QB, NH), gb, 0, stream, Qb, Kb, Vb, ctxb);
  // output projection (fp32 out)
  hipLaunchKernelGGL(k_f32_to_bf16, dim3(EMB * EMB / 2048), dim3(256), 0, stream, wo, wb, EMB * EMB);
  hipLaunchKernelGGL(k_gemm_bf16, gg, gb, 0, stream, ctxb, wb, bo, d_out, SEQ, EMB, EMB, 1);
}

// Round 4
// 601.861 us; speedup vs baseline: 2.1539x; 1.1830x over previous
//
#include <hip/hip_runtime.h>
#include <hip/hip_bf16.h>

constexpr int SEQ = 2048;
constexpr int EMB = 4096;
constexpr int NH  = 32;
constexpr int HD  = 128;
constexpr int HALF = 64;

typedef __bf16 bf16x8 __attribute__((ext_vector_type(8)));
typedef float  f32x4  __attribute__((ext_vector_type(4)));
using u16 = unsigned short;
typedef u16 ushort8 __attribute__((ext_vector_type(8)));
typedef u16 u16x4 __attribute__((ext_vector_type(4)));

__device__ inline float bf2f(u16 u) {
  union { unsigned int i; float f; } v; v.i = ((unsigned int)u) << 16; return v.f;
}
__device__ inline u16 f2bf(float f) {
  union { __bf16 b; u16 u; } v; v.b = (__bf16)f; return v.u;
}

// ---------------- fp32 -> bf16 conversion (vectorized) ----------------
__global__ void k_f32_to_bf16(const float* __restrict__ in, u16* __restrict__ out, int n) {
  int i = (blockIdx.x * blockDim.x + threadIdx.x) * 8;
  if (i >= n) return;
  f32x4 a = *(const f32x4*)(in + i);
  f32x4 b = *(const f32x4*)(in + i + 4);
  ushort8 o;
  o[0] = f2bf(a[0]); o[1] = f2bf(a[1]); o[2] = f2bf(a[2]); o[3] = f2bf(a[3]);
  o[4] = f2bf(b[0]); o[5] = f2bf(b[1]); o[6] = f2bf(b[2]); o[7] = f2bf(b[3]);
  *(ushort8*)(out + i) = o;
}

// ---------------- RoPE cos/sin table (fp64 for exactness) ----------------
__global__ void k_rope_table(const int* __restrict__ pos, float* __restrict__ tab) {
  int idx = blockIdx.x * blockDim.x + threadIdx.x;
  if (idx >= SEQ * HALF) return;
  int s = idx >> 6, d = idx & 63;
  double invf = pow(10000.0, -(double)d / 64.0);
  double ang = (double)pos[s] * invf;
  tab[idx * 2]     = (float)cos(ang);
  tab[idx * 2 + 1] = (float)sin(ang);
}

// ---------------- RoPE apply (in-place on bf16, optional 1/sqrt(D) fold) ----------------
__global__ void k_rope(u16* __restrict__ X, const float* __restrict__ tab, float scale) {
  int idx = blockIdx.x * blockDim.x + threadIdx.x;   // SEQ*NH*HALF
  if (idx >= SEQ * NH * HALF) return;
  int d = idx & 63;
  int h = (idx >> 6) & 31;
  int s = idx >> 11;
  u16* p = X + (size_t)s * EMB + h * HD + d;
  float x1 = bf2f(p[0]), x2 = bf2f(p[HALF]);
  float c  = tab[(s * HALF + d) * 2];
  float sn = tab[(s * HALF + d) * 2 + 1];
  p[0]    = f2bf((x1 * c - x2 * sn) * scale);
  p[HALF] = f2bf((x2 * c + x1 * sn) * scale);
}

// ---------------- bf16 MFMA GEMM (m97 structure):  C = A[M][K] * W[N][K]^T + bias ----------------
// 128x128 tile, BK=32, 4 waves (2x2), linear LDS [128][32], global_load_lds width=16.
// out_mode: 0 = bf16 [M][N], 1 = f32 [M][N], 2 = bf16 transposed [N][M] (for V^T)
constexpr int BM = 128, BN = 128, BK = 32;

__global__ __launch_bounds__(256) void k_gemm_bf16(
    const u16* __restrict__ A, const u16* __restrict__ W, const float* __restrict__ bias,
    void* __restrict__ Cout, int M, int N, int K, int out_mode)
{
  __shared__ alignas(16) u16 As[BM * BK];
  __shared__ alignas(16) u16 Bs[BN * BK];
  int tid = threadIdx.x;
  int lane = tid & 63, wid = tid >> 6;
  int wm = wid >> 1, wn = wid & 1;
  int l15 = lane & 15, lhi = lane >> 4;

  // bijective XCD swizzle (nwg % 8 == 0 here: 32*16=512)
  int nwg = gridDim.x * gridDim.y;
  int lin = blockIdx.y * gridDim.x + blockIdx.x;
  int cpx = nwg >> 3;
  int swz = (lin & 7) * cpx + (lin >> 3);
  int bx = swz % gridDim.x, by = swz / gridDim.x;
  int m0 = by * BM, n0 = bx * BN;

  f32x4 acc[4][4] = {};

  int srow = (lane >> 2);          // 0..15 within chunk
  int scol = (lane & 3) * 8;       // 0,8,16,24

  for (int k0 = 0; k0 < K; k0 += BK) {
    __syncthreads();   // previous tile fully consumed
#pragma unroll
    for (int i = 0; i < 2; i++) {
      int chunk = wid * 2 + i;               // 0..7
      int row = chunk * 16 + srow;
      __builtin_amdgcn_global_load_lds(
          (const __attribute__((address_space(1))) void*)(A + (size_t)(m0 + row) * K + k0 + scol),
          (__attribute__((address_space(3))) void*)(As + chunk * 512), 16, 0, 0);
      __builtin_amdgcn_global_load_lds(
          (const __attribute__((address_space(1))) void*)(W + (size_t)(n0 + row) * K + k0 + scol),
          (__attribute__((address_space(3))) void*)(Bs + chunk * 512), 16, 0, 0);
    }
    __syncthreads();   // vmcnt(0) drained before barrier -> data visible

    bf16x8 af[4], bfr[4];
#pragma unroll
    for (int a = 0; a < 4; a++)
      af[a] = *(const bf16x8*)&As[(wm * 64 + a * 16 + l15) * BK + lhi * 8];
#pragma unroll
    for (int b = 0; b < 4; b++)
      bfr[b] = *(const bf16x8*)&Bs[(wn * 64 + b * 16 + l15) * BK + lhi * 8];
#pragma unroll
    for (int a = 0; a < 4; a++)
#pragma unroll
      for (int b = 0; b < 4; b++)
        acc[a][b] = __builtin_amdgcn_mfma_f32_16x16x32_bf16(af[a], bfr[b], acc[a][b], 0, 0, 0);
  }

#pragma unroll
  for (int a = 0; a < 4; a++) {
    int m = m0 + wm * 64 + a * 16 + lhi * 4;
#pragma unroll
    for (int b = 0; b < 4; b++) {
      int n = n0 + wn * 64 + b * 16 + l15;
      float bs = bias[n];
      if (out_mode == 2) {
        u16x4 pk;
#pragma unroll
        for (int r = 0; r < 4; r++) pk[r] = f2bf(acc[a][b][r] + bs);
        *(u16x4*)&((u16*)Cout)[(size_t)n * M + m] = pk;   // V^T: row n, 4 contiguous m
      } else if (out_mode == 1) {
#pragma unroll
        for (int r = 0; r < 4; r++)
          ((float*)Cout)[(size_t)(m + r) * N + n] = acc[a][b][r] + bs;
      } else {
#pragma unroll
        for (int r = 0; r < 4; r++)
          ((u16*)Cout)[(size_t)(m + r) * N + n] = f2bf(acc[a][b][r] + bs);
      }
    }
  }
}

// ---------------- Flash attention (causal), bf16 MFMA, fp32 softmax ----------------
// QB=64 (4 waves x 16 rows), KVB=64. Paired q-blocks (qb, 31-qb): uniform 33 tiles/block.
// K and V^T staged via global_load_lds into double-buffered LDS with block-rotated layouts
// (rotation folded into the per-lane GLOBAL source address; LDS dest stays linear).
//   Ks: addr(r,b')  = r*128 + b'*8, content blk = (b'-r)&15   -> QK reads conflict-free
//   Vt: addr(d,b')  = d*64  + b'*8, content blk = (b'-d)&7    -> PV reads conflict-free
//   Pl: addr(q,kb)  = q*64 + ((kb + (q>>1))&7)*8              -> scatter writes ~2-way
constexpr int QB = 64, KVB = 64;

__global__ __launch_bounds__(256) void k_flash(
    const u16* __restrict__ Q, const u16* __restrict__ K, const u16* __restrict__ VT,
    u16* __restrict__ ctx)
{
  __shared__ alignas(16) u16 Ks[2][KVB * 128];
  __shared__ alignas(16) u16 Vt[2][HD * 64];
  __shared__ alignas(16) u16 Pl[4][16 * 64];

  int tid = threadIdx.x, lane = tid & 63, wid = tid >> 6;
  int l15 = lane & 15, lhi = lane >> 4;
  int h = blockIdx.y;

  auto stage = [&](int buf, int t2) {
    int kv = t2 * KVB;
#pragma unroll
    for (int it = 0; it < 4; it++) {
      int chunk = tid + it * 256;          // 0..1023
      int r = chunk >> 4, bp = chunk & 15;
      __builtin_amdgcn_global_load_lds(
        (const __attribute__((address_space(1))) void*)(K + (size_t)(kv + r) * EMB + h * HD + (((bp - r) & 15) << 3)),
        (__attribute__((address_space(3))) void*)(&Ks[buf][chunk * 8]), 16, 0, 0);
    }
#pragma unroll
    for (int it = 0; it < 4; it++) {
      int chunk = tid + it * 256;
      int d = chunk >> 3, bp = chunk & 7;
      __builtin_amdgcn_global_load_lds(
        (const __attribute__((address_space(1))) void*)(VT + (size_t)(h * HD + d) * SEQ + kv + (((bp - d) & 7) << 3)),
        (__attribute__((address_space(3))) void*)(&Vt[buf][chunk * 8]), 16, 0, 0);
    }
  };

  for (int pi = 0; pi < 2; pi++) {
    int qb = pi ? (int)blockIdx.x : 31 - (int)blockIdx.x;
    int q0 = qb * QB;
    int qw = q0 + wid * 16;

    bf16x8 qf[4];
#pragma unroll
    for (int kc = 0; kc < 4; kc++)
      qf[kc] = *(const bf16x8*)&Q[(size_t)(qw + l15) * EMB + h * HD + kc * 32 + lhi * 8];

    f32x4 O[8] = {};
    float mrow[4], lrow[4];
#pragma unroll
    for (int r = 0; r < 4; r++) { mrow[r] = -3.0e38f; lrow[r] = 0.f; }

    int nt = qb + 1;
    __syncthreads();          // pass boundary: previous pass's LDS reads done
    stage(0, 0);
    for (int t = 0; t < nt; t++) {
      __syncthreads();        // drains stage(t) loads (vmcnt 0); prior compute done
      if (t + 1 < nt) stage((t + 1) & 1, t + 1);   // lands during compute(t)

      const u16* ks = Ks[t & 1];
      const u16* vt = Vt[t & 1];
      float p[4][4];
      bool need_mask = (t == nt - 1);   // only the diagonal tile needs masking
#pragma unroll
      for (int c = 0; c < 4; c++) {
        f32x4 s = {};
        int r0 = c * 16 + l15;
#pragma unroll
        for (int kc = 0; kc < 4; kc++) {
          bf16x8 kf = *(const bf16x8*)&ks[r0 * 128 + (((kc * 4 + lhi) + r0) & 15) * 8];
          s = __builtin_amdgcn_mfma_f32_16x16x32_bf16(qf[kc], kf, s, 0, 0, 0);
        }
#pragma unroll
        for (int r = 0; r < 4; r++) {
          float sv = s[r];
          if (need_mask) {
            int qg = qw + lhi * 4 + r;
            int kg = t * KVB + c * 16 + l15;
            if (kg > qg) sv = -3.0e38f;
          }
          p[c][r] = sv;
        }
      }
      // online softmax (row r lives across the 16 l15 lanes of each lhi group)
      float fscale[4];
#pragma unroll
      for (int r = 0; r < 4; r++) {
        float m = fmaxf(fmaxf(p[0][r], p[1][r]), fmaxf(p[2][r], p[3][r]));
#pragma unroll
        for (int x = 1; x < 16; x <<= 1) m = fmaxf(m, __shfl_xor(m, x, 64));
        float mnew = fmaxf(mrow[r], m);
        fscale[r] = __expf(mrow[r] - mnew);
        mrow[r] = mnew;
      }
#pragma unroll
      for (int c = 0; c < 4; c++)
#pragma unroll
        for (int r = 0; r < 4; r++)
          p[c][r] = __expf(p[c][r] - mrow[r]);
#pragma unroll
      for (int r = 0; r < 4; r++) {
        float s = p[0][r] + p[1][r] + p[2][r] + p[3][r];
#pragma unroll
        for (int x = 1; x < 16; x <<= 1) s += __shfl_xor(s, x, 64);
        lrow[r] = lrow[r] * fscale[r] + s;
      }
#pragma unroll
      for (int d = 0; d < 8; d++)
#pragma unroll
        for (int r = 0; r < 4; r++)
          O[d][r] *= fscale[r];
      // P -> wave-private LDS (same wave reads back; no barrier)
#pragma unroll
      for (int c = 0; c < 4; c++) {
        int kb = c * 2 + (l15 >> 3), klo = l15 & 7;
#pragma unroll
        for (int r = 0; r < 4; r++) {
          int q = lhi * 4 + r;
          Pl[wid][q * 64 + ((kb + (q >> 1)) & 7) * 8 + klo] = f2bf(p[c][r]);
        }
      }
#pragma unroll
      for (int ks2 = 0; ks2 < 2; ks2++) {
        int kb = ks2 * 4 + lhi;
        bf16x8 pf = *(const bf16x8*)&Pl[wid][l15 * 64 + ((kb + (l15 >> 1)) & 7) * 8];
#pragma unroll
        for (int ds = 0; ds < 8; ds++) {
          int d = ds * 16 + l15;
          bf16x8 vf = *(const bf16x8*)&vt[d * 64 + ((kb + d) & 7) * 8];
          O[ds] = __builtin_amdgcn_mfma_f32_16x16x32_bf16(pf, vf, O[ds], 0, 0, 0);
        }
      }
    }

#pragma unroll
    for (int r = 0; r < 4; r++) {
      float inv = 1.f / lrow[r];
      int qg = q0 + wid * 16 + lhi * 4 + r;
#pragma unroll
      for (int ds = 0; ds < 8; ds++)
        ctx[(size_t)qg * EMB + h * HD + ds * 16 + l15] = f2bf(O[ds][r] * inv);
    }
  }
}

// ---------------- launch ----------------
extern "C" void kernel_launch(void* const* d_in, const int* in_sizes, int n_in,
                              void* d_out, int out_size, void* d_ws, size_t ws_size,
                              hipStream_t stream) {
  const float* hs = (const float*)d_in[0];
  const float* wq = (const float*)d_in[1];
  const float* bq = (const float*)d_in[2];
  const float* wk = (const float*)d_in[3];
  const float* bk = (const float*)d_in[4];
  const float* wv = (const float*)d_in[5];
  const float* bv = (const float*)d_in[6];
  const float* wo = (const float*)d_in[7];
  const float* bo = (const float*)d_in[8];
  const int*  pos = (const int*)d_in[9];

  char* ws = (char*)d_ws;
  size_t off = 0;
  auto alloc = [&](size_t b) { size_t o = off; off += (b + 255) & ~(size_t)255; return o; };
  u16*  hsb  = (u16*)(ws + alloc((size_t)SEQ * EMB * 2));
  u16*  wb   = (u16*)(ws + alloc((size_t)EMB * EMB * 2));   // reused for wq/wk/wv/wo
  u16*  Qb   = (u16*)(ws + alloc((size_t)SEQ * EMB * 2));
  u16*  Kb   = (u16*)(ws + alloc((size_t)SEQ * EMB * 2));
  u16*  VTb  = (u16*)(ws + alloc((size_t)SEQ * EMB * 2));   // V^T, [E][S]
  u16*  ctxb = (u16*)(ws + alloc((size_t)SEQ * EMB * 2));
  float* tab = (float*)(ws + alloc((size_t)SEQ * HALF * 2 * 4));

  const float qscale = 1.0f / 11.313708498984761f;  // 1/sqrt(128)

  hipLaunchKernelGGL(k_f32_to_bf16, dim3(SEQ * EMB / 2048), dim3(256), 0, stream, hs, hsb, SEQ * EMB);
  hipLaunchKernelGGL(k_rope_table, dim3(SEQ * HALF / 256), dim3(256), 0, stream, pos, tab);

  dim3 gg(EMB / BN, SEQ / BM);
  dim3 gb(256);

  // Q
  hipLaunchKernelGGL(k_f32_to_bf16, dim3(EMB * EMB / 2048), dim3(256), 0, stream, wq, wb, EMB * EMB);
  hipLaunchKernelGGL(k_gemm_bf16, gg, gb, 0, stream, hsb, wb, bq, (void*)Qb, SEQ, EMB, EMB, 0);
  // K
  hipLaunchKernelGGL(k_f32_to_bf16, dim3(EMB * EMB / 2048), dim3(256), 0, stream, wk, wb, EMB * EMB);
  hipLaunchKernelGGL(k_gemm_bf16, gg, gb, 0, stream, hsb, wb, bk, (void*)Kb, SEQ, EMB, EMB, 0);
  // RoPE on Q (with 1/sqrt(D) folded) and K
  hipLaunchKernelGGL(k_rope, dim3(SEQ * NH * HALF / 256), dim3(256), 0, stream, Qb, tab, qscale);
  hipLaunchKernelGGL(k_rope, dim3(SEQ * NH * HALF / 256), dim3(256), 0, stream, Kb, tab, 1.0f);
  // V -> V^T directly from the GEMM epilogue
  hipLaunchKernelGGL(k_f32_to_bf16, dim3(EMB * EMB / 2048), dim3(256), 0, stream, wv, wb, EMB * EMB);
  hipLaunchKernelGGL(k_gemm_bf16, gg, gb, 0, stream, hsb, wb, bv, (void*)VTb, SEQ, EMB, EMB, 2);
  // attention (paired q-blocks: grid.x = 16)
  hipLaunchKernelGGL(k_flash, dim3(16, NH), gb, 0, stream, Qb, Kb, VTb, ctxb);
  // output projection (fp32 out)
  hipLaunchKernelGGL(k_f32_to_bf16, dim3(EMB * EMB / 2048), dim3(256), 0, stream, wo, wb, EMB * EMB);
  hipLaunchKernelGGL(k_gemm_bf16, gg, gb, 0, stream, ctxb, wb, bo, d_out, SEQ, EMB, EMB, 1);
}

// Round 5
// 577.424 us; speedup vs baseline: 2.2451x; 1.0423x over previous
//
#include <hip/hip_runtime.h>
#include <hip/hip_bf16.h>

constexpr int SEQ = 2048;
constexpr int EMB = 4096;
constexpr int NH  = 32;
constexpr int HD  = 128;
constexpr int HALF = 64;

typedef __bf16 bf16x8 __attribute__((ext_vector_type(8)));
typedef float  f32x4  __attribute__((ext_vector_type(4)));
using u16 = unsigned short;
typedef u16 ushort8 __attribute__((ext_vector_type(8)));
typedef u16 u16x4 __attribute__((ext_vector_type(4)));

__device__ inline float bf2f(u16 u) {
  union { unsigned int i; float f; } v; v.i = ((unsigned int)u) << 16; return v.f;
}
__device__ inline u16 f2bf(float f) {
  union { __bf16 b; u16 u; } v; v.b = (__bf16)f; return v.u;
}

#define GLL16(gp, lp) __builtin_amdgcn_global_load_lds( \
    (const __attribute__((address_space(1))) void*)(gp), \
    (__attribute__((address_space(3))) void*)(lp), 16, 0, 0)

// ---------------- fp32 -> bf16 conversion (vectorized) ----------------
__global__ void k_f32_to_bf16(const float* __restrict__ in, u16* __restrict__ out, int n) {
  int i = (blockIdx.x * blockDim.x + threadIdx.x) * 8;
  if (i >= n) return;
  f32x4 a = *(const f32x4*)(in + i);
  f32x4 b = *(const f32x4*)(in + i + 4);
  ushort8 o;
  o[0] = f2bf(a[0]); o[1] = f2bf(a[1]); o[2] = f2bf(a[2]); o[3] = f2bf(a[3]);
  o[4] = f2bf(b[0]); o[5] = f2bf(b[1]); o[6] = f2bf(b[2]); o[7] = f2bf(b[3]);
  *(ushort8*)(out + i) = o;
}

// ---------------- RoPE cos/sin table (fp64 for exactness) ----------------
__global__ void k_rope_table(const int* __restrict__ pos, float* __restrict__ tab) {
  int idx = blockIdx.x * blockDim.x + threadIdx.x;
  if (idx >= SEQ * HALF) return;
  int s = idx >> 6, d = idx & 63;
  double invf = pow(10000.0, -(double)d / 64.0);
  double ang = (double)pos[s] * invf;
  tab[idx * 2]     = (float)cos(ang);
  tab[idx * 2 + 1] = (float)sin(ang);
}

// ---------------- RoPE apply (in-place on bf16, optional 1/sqrt(D) fold) ----------------
__global__ void k_rope(u16* __restrict__ X, const float* __restrict__ tab, float scale) {
  int idx = blockIdx.x * blockDim.x + threadIdx.x;   // SEQ*NH*HALF
  if (idx >= SEQ * NH * HALF) return;
  int d = idx & 63;
  int h = (idx >> 6) & 31;
  int s = idx >> 11;
  u16* p = X + (size_t)s * EMB + h * HD + d;
  float x1 = bf2f(p[0]), x2 = bf2f(p[HALF]);
  float c  = tab[(s * HALF + d) * 2];
  float sn = tab[(s * HALF + d) * 2 + 1];
  p[0]    = f2bf((x1 * c - x2 * sn) * scale);
  p[HALF] = f2bf((x2 * c + x1 * sn) * scale);
}

// ---------------- bf16 MFMA GEMM (m97 structure), templated tile ----------------
// C = A[M][K] * W[N][K]^T + bias. 2x2 waves; BK=32; linear LDS; global_load_lds w=16.
// mode: 0 = bf16 [M][Nn], 1 = f32 [M][Nn], 2 = bf16 transposed [n][M],
//       3 = QKV fused (N=12288; seg by n0>>12: 0->C0 bf16, 1->C1 bf16, 2->C2 V^T)
template<int TBM, int TBN>
__global__ __launch_bounds__(256) void k_gemm(
    const u16* __restrict__ A, const u16* __restrict__ W,
    const float* __restrict__ b0, const float* __restrict__ b1, const float* __restrict__ b2,
    void* __restrict__ C0, void* __restrict__ C1, void* __restrict__ C2,
    int M, int N, int K, int mode)
{
  constexpr int CH_A = TBM / 16, CH_B = TBN / 16;
  constexpr int CH_W = (CH_A + CH_B) / 4;         // chunks (512 elems) per wave
  constexpr int MA = TBM / 32, NB = TBN / 32;     // frags per wave
  __shared__ alignas(16) u16 As[TBM * 32];
  __shared__ alignas(16) u16 Bs[TBN * 32];
  int tid = threadIdx.x;
  int lane = tid & 63, wid = tid >> 6;
  int wm = wid >> 1, wn = wid & 1;
  int l15 = lane & 15, lhi = lane >> 4;

  // bijective XCD swizzle (all grids here have nwg % 8 == 0)
  int nwg = gridDim.x * gridDim.y;
  int lin = blockIdx.y * gridDim.x + blockIdx.x;
  int cpx = nwg >> 3;
  int swz = (lin & 7) * cpx + (lin >> 3);
  int bx = swz % gridDim.x, by = swz / gridDim.x;
  int m0 = by * TBM, n0 = bx * TBN;

  f32x4 acc[MA][NB] = {};

  int srow = lane >> 2;            // 0..15 within chunk
  int scol = (lane & 3) * 8;       // 0,8,16,24

  for (int k0 = 0; k0 < K; k0 += 32) {
    __syncthreads();
#pragma unroll
    for (int i = 0; i < CH_W; i++) {
      int chunk = wid * CH_W + i;
      if (chunk < CH_A) {
        int row = chunk * 16 + srow;
        GLL16(A + (size_t)(m0 + row) * K + k0 + scol, As + chunk * 512);
      } else {
        int c2 = chunk - CH_A;
        int row = c2 * 16 + srow;
        GLL16(W + (size_t)(n0 + row) * K + k0 + scol, Bs + c2 * 512);
      }
    }
    __syncthreads();

    bf16x8 af[MA], bfr[NB];
#pragma unroll
    for (int a = 0; a < MA; a++)
      af[a] = *(const bf16x8*)&As[(wm * (TBM / 2) + a * 16 + l15) * 32 + lhi * 8];
#pragma unroll
    for (int b = 0; b < NB; b++)
      bfr[b] = *(const bf16x8*)&Bs[(wn * (TBN / 2) + b * 16 + l15) * 32 + lhi * 8];
#pragma unroll
    for (int a = 0; a < MA; a++)
#pragma unroll
      for (int b = 0; b < NB; b++)
        acc[a][b] = __builtin_amdgcn_mfma_f32_16x16x32_bf16(af[a], bfr[b], acc[a][b], 0, 0, 0);
  }

  // epilogue: resolve output segment
  const float* bias = b0;
  void* Cout = C0;
  int mode_l = mode, Nn = N, n_base = n0;
  if (mode == 3) {
    int seg = n0 >> 12;
    Nn = EMB; n_base = n0 & 4095;
    if (seg == 0)      { bias = b0; Cout = C0; mode_l = 0; }
    else if (seg == 1) { bias = b1; Cout = C1; mode_l = 0; }
    else               { bias = b2; Cout = C2; mode_l = 2; }
  }

#pragma unroll
  for (int a = 0; a < MA; a++) {
    int m = m0 + wm * (TBM / 2) + a * 16 + lhi * 4;
#pragma unroll
    for (int b = 0; b < NB; b++) {
      int n = n_base + wn * (TBN / 2) + b * 16 + l15;
      float bs = bias[n];
      if (mode_l == 2) {
        u16x4 pk;
#pragma unroll
        for (int r = 0; r < 4; r++) pk[r] = f2bf(acc[a][b][r] + bs);
        *(u16x4*)&((u16*)Cout)[(size_t)n * M + m] = pk;
      } else if (mode_l == 1) {
#pragma unroll
        for (int r = 0; r < 4; r++)
          ((float*)Cout)[(size_t)(m + r) * Nn + n] = acc[a][b][r] + bs;
      } else {
#pragma unroll
        for (int r = 0; r < 4; r++)
          ((u16*)Cout)[(size_t)(m + r) * Nn + n] = f2bf(acc[a][b][r] + bs);
      }
    }
  }
}

// ---------------- Flash attention (causal), bf16 MFMA, fp32 softmax ----------------
// QB=64 (4 waves x 16 rows), KVB=64. Paired q-blocks (qb, 31-qb): uniform 33 tiles/block.
// K and V^T staged via global_load_lds into double-buffered LDS with block-rotated layouts
// (rotation folded into the per-lane GLOBAL source address; LDS dest stays linear).
constexpr int QB = 64, KVB = 64;

__global__ __launch_bounds__(256) void k_flash(
    const u16* __restrict__ Q, const u16* __restrict__ K, const u16* __restrict__ VT,
    u16* __restrict__ ctx)
{
  __shared__ alignas(16) u16 Ks[2][KVB * 128];
  __shared__ alignas(16) u16 Vt[2][HD * 64];
  __shared__ alignas(16) u16 Pl[4][16 * 64];

  int tid = threadIdx.x, lane = tid & 63, wid = tid >> 6;
  int l15 = lane & 15, lhi = lane >> 4;
  int h = blockIdx.y;

  auto stage = [&](int buf, int t2) {
    int kv = t2 * KVB;
#pragma unroll
    for (int it = 0; it < 4; it++) {
      int chunk = tid + it * 256;          // 0..1023
      int r = chunk >> 4, bp = chunk & 15;
      GLL16(K + (size_t)(kv + r) * EMB + h * HD + (((bp - r) & 15) << 3), &Ks[buf][chunk * 8]);
    }
#pragma unroll
    for (int it = 0; it < 4; it++) {
      int chunk = tid + it * 256;
      int d = chunk >> 3, bp = chunk & 7;
      GLL16(VT + (size_t)(h * HD + d) * SEQ + kv + (((bp - d) & 7) << 3), &Vt[buf][chunk * 8]);
    }
  };

  for (int pi = 0; pi < 2; pi++) {
    int qb = pi ? (int)blockIdx.x : 31 - (int)blockIdx.x;
    int q0 = qb * QB;
    int qw = q0 + wid * 16;

    bf16x8 qf[4];
#pragma unroll
    for (int kc = 0; kc < 4; kc++)
      qf[kc] = *(const bf16x8*)&Q[(size_t)(qw + l15) * EMB + h * HD + kc * 32 + lhi * 8];

    f32x4 O[8] = {};
    float mrow[4], lrow[4];
#pragma unroll
    for (int r = 0; r < 4; r++) { mrow[r] = -3.0e38f; lrow[r] = 0.f; }

    int nt = qb + 1;
    __syncthreads();          // pass boundary: previous pass's LDS reads done
    stage(0, 0);
    for (int t = 0; t < nt; t++) {
      __syncthreads();        // drains stage(t) loads; prior compute done
      if (t + 1 < nt) stage((t + 1) & 1, t + 1);   // lands during compute(t)

      const u16* ks = Ks[t & 1];
      const u16* vt = Vt[t & 1];
      float p[4][4];
      bool need_mask = (t == nt - 1);   // only the diagonal tile needs masking
#pragma unroll
      for (int c = 0; c < 4; c++) {
        f32x4 s = {};
        int r0 = c * 16 + l15;
#pragma unroll
        for (int kc = 0; kc < 4; kc++) {
          bf16x8 kf = *(const bf16x8*)&ks[r0 * 128 + (((kc * 4 + lhi) + r0) & 15) * 8];
          s = __builtin_amdgcn_mfma_f32_16x16x32_bf16(qf[kc], kf, s, 0, 0, 0);
        }
#pragma unroll
        for (int r = 0; r < 4; r++) {
          float sv = s[r];
          if (need_mask) {
            int qg = qw + lhi * 4 + r;
            int kg = t * KVB + c * 16 + l15;
            if (kg > qg) sv = -3.0e38f;
          }
          p[c][r] = sv;
        }
      }
      float fscale[4];
#pragma unroll
      for (int r = 0; r < 4; r++) {
        float m = fmaxf(fmaxf(p[0][r], p[1][r]), fmaxf(p[2][r], p[3][r]));
#pragma unroll
        for (int x = 1; x < 16; x <<= 1) m = fmaxf(m, __shfl_xor(m, x, 64));
        float mnew = fmaxf(mrow[r], m);
        fscale[r] = __expf(mrow[r] - mnew);
        mrow[r] = mnew;
      }
#pragma unroll
      for (int c = 0; c < 4; c++)
#pragma unroll
        for (int r = 0; r < 4; r++)
          p[c][r] = __expf(p[c][r] - mrow[r]);
#pragma unroll
      for (int r = 0; r < 4; r++) {
        float s = p[0][r] + p[1][r] + p[2][r] + p[3][r];
#pragma unroll
        for (int x = 1; x < 16; x <<= 1) s += __shfl_xor(s, x, 64);
        lrow[r] = lrow[r] * fscale[r] + s;
      }
#pragma unroll
      for (int d = 0; d < 8; d++)
#pragma unroll
        for (int r = 0; r < 4; r++)
          O[d][r] *= fscale[r];
#pragma unroll
      for (int c = 0; c < 4; c++) {
        int kb = c * 2 + (l15 >> 3), klo = l15 & 7;
#pragma unroll
        for (int r = 0; r < 4; r++) {
          int q = lhi * 4 + r;
          Pl[wid][q * 64 + ((kb + (q >> 1)) & 7) * 8 + klo] = f2bf(p[c][r]);
        }
      }
#pragma unroll
      for (int ks2 = 0; ks2 < 2; ks2++) {
        int kb = ks2 * 4 + lhi;
        bf16x8 pf = *(const bf16x8*)&Pl[wid][l15 * 64 + ((kb + (l15 >> 1)) & 7) * 8];
#pragma unroll
        for (int ds = 0; ds < 8; ds++) {
          int d = ds * 16 + l15;
          bf16x8 vf = *(const bf16x8*)&vt[d * 64 + ((kb + d) & 7) * 8];
          O[ds] = __builtin_amdgcn_mfma_f32_16x16x32_bf16(pf, vf, O[ds], 0, 0, 0);
        }
      }
    }

#pragma unroll
    for (int r = 0; r < 4; r++) {
      float inv = 1.f / lrow[r];
      int qg = q0 + wid * 16 + lhi * 4 + r;
#pragma unroll
      for (int ds = 0; ds < 8; ds++)
        ctx[(size_t)qg * EMB + h * HD + ds * 16 + l15] = f2bf(O[ds][r] * inv);
    }
  }
}

// ---------------- launch ----------------
extern "C" void kernel_launch(void* const* d_in, const int* in_sizes, int n_in,
                              void* d_out, int out_size, void* d_ws, size_t ws_size,
                              hipStream_t stream) {
  const float* hs = (const float*)d_in[0];
  const float* wq = (const float*)d_in[1];
  const float* bq = (const float*)d_in[2];
  const float* wk = (const float*)d_in[3];
  const float* bk = (const float*)d_in[4];
  const float* wv = (const float*)d_in[5];
  const float* bv = (const float*)d_in[6];
  const float* wo = (const float*)d_in[7];
  const float* bo = (const float*)d_in[8];
  const int*  pos = (const int*)d_in[9];

  const size_t SE = (size_t)SEQ * EMB;   // 8M elems
  const size_t EE = (size_t)EMB * EMB;   // 16M elems
  const float qscale = 1.0f / 11.313708498984761f;  // 1/sqrt(128)

  char* ws = (char*)d_ws;
  size_t off = 0;
  auto alloc = [&](size_t b) { size_t o = off; off += (b + 255) & ~(size_t)255; return o; };

  size_t need_fused = ((SE * 2 + 255) & ~255ULL) + ((EE * 6 + 255) & ~255ULL) +
                      3 * ((SE * 2 + 255) & ~255ULL) + ((size_t)SEQ * HALF * 8 + 255);
  bool fused = ws_size >= need_fused + 4096;

  u16*  hsb = (u16*)(ws + alloc(SE * 2));
  u16*  wb  = (u16*)(ws + alloc(fused ? EE * 6 : EE * 2));  // fused: wq|wk|wv, reused for wo
  u16*  Qb  = (u16*)(ws + alloc(SE * 2));
  u16*  Kb  = (u16*)(ws + alloc(SE * 2));
  u16*  VTb = (u16*)(ws + alloc(SE * 2));                   // V^T, [E][S]
  float* tab = (float*)(ws + alloc((size_t)SEQ * HALF * 2 * 4));
  u16*  ctxb = hsb;   // hs dead after QKV GEMM; flash output reuses it

  dim3 cb(256);
  k_f32_to_bf16<<<dim3(SE / 2048), cb, 0, stream>>>(hs, hsb, (int)SE);
  k_rope_table<<<dim3(SEQ * HALF / 256), cb, 0, stream>>>(pos, tab);

  if (fused) {
    k_f32_to_bf16<<<dim3(EE / 2048), cb, 0, stream>>>(wq, wb, (int)EE);
    k_f32_to_bf16<<<dim3(EE / 2048), cb, 0, stream>>>(wk, wb + EE, (int)EE);
    k_f32_to_bf16<<<dim3(EE / 2048), cb, 0, stream>>>(wv, wb + 2 * EE, (int)EE);
    // fused QKV GEMM: N = 12288, grid 96x16 = 1536 wg (6 blocks/CU)
    k_gemm<128, 128><<<dim3(96, 16), cb, 0, stream>>>(
        hsb, wb, bq, bk, bv, (void*)Qb, (void*)Kb, (void*)VTb, SEQ, 3 * EMB, EMB, 3);
  } else {
    k_f32_to_bf16<<<dim3(EE / 2048), cb, 0, stream>>>(wq, wb, (int)EE);
    k_gemm<128, 128><<<dim3(32, 16), cb, 0, stream>>>(
        hsb, wb, bq, bq, bq, (void*)Qb, nullptr, nullptr, SEQ, EMB, EMB, 0);
    k_f32_to_bf16<<<dim3(EE / 2048), cb, 0, stream>>>(wk, wb, (int)EE);
    k_gemm<128, 128><<<dim3(32, 16), cb, 0, stream>>>(
        hsb, wb, bk, bk, bk, (void*)Kb, nullptr, nullptr, SEQ, EMB, EMB, 0);
    k_f32_to_bf16<<<dim3(EE / 2048), cb, 0, stream>>>(wv, wb, (int)EE);
    k_gemm<128, 128><<<dim3(32, 16), cb, 0, stream>>>(
        hsb, wb, bv, bv, bv, (void*)VTb, nullptr, nullptr, SEQ, EMB, EMB, 2);
  }

  k_rope<<<dim3(SEQ * NH * HALF / 256), cb, 0, stream>>>(Qb, tab, qscale);
  k_rope<<<dim3(SEQ * NH * HALF / 256), cb, 0, stream>>>(Kb, tab, 1.0f);

  // attention (paired q-blocks: grid.x = 16)
  k_flash<<<dim3(16, NH), cb, 0, stream>>>(Qb, Kb, VTb, ctxb);

  // output projection: 64x128 tile -> 1024 wg (4 blocks/CU), f32 out
  k_f32_to_bf16<<<dim3(EE / 2048), cb, 0, stream>>>(wo, wb, (int)EE);
  k_gemm<64, 128><<<dim3(32, 32), cb, 0, stream>>>(
      ctxb, wb, bo, bo, bo, d_out, nullptr, nullptr, SEQ, EMB, EMB, 1);
}

// Round 6
// 553.545 us; speedup vs baseline: 2.3419x; 1.0431x over previous
//
#include <hip/hip_runtime.h>
#include <hip/hip_bf16.h>

constexpr int SEQ = 2048;
constexpr int EMB = 4096;
constexpr int NH  = 32;
constexpr int HD  = 128;
constexpr int HALF = 64;

typedef __bf16 bf16x8 __attribute__((ext_vector_type(8)));
typedef float  f32x4  __attribute__((ext_vector_type(4)));
using u16 = unsigned short;
typedef u16 ushort8 __attribute__((ext_vector_type(8)));
typedef u16 u16x4 __attribute__((ext_vector_type(4)));

__device__ inline float bf2f(u16 u) {
  union { unsigned int i; float f; } v; v.i = ((unsigned int)u) << 16; return v.f;
}
__device__ inline u16 f2bf(float f) {
  union { __bf16 b; u16 u; } v; v.b = (__bf16)f; return v.u;
}

#define GLL16(gp, lp) __builtin_amdgcn_global_load_lds( \
    (const __attribute__((address_space(1))) void*)(gp), \
    (__attribute__((address_space(3))) void*)(lp), 16, 0, 0)

// ---------------- fp32 -> bf16 conversion (vectorized) ----------------
__global__ void k_f32_to_bf16(const float* __restrict__ in, u16* __restrict__ out, int n) {
  int i = (blockIdx.x * blockDim.x + threadIdx.x) * 8;
  if (i >= n) return;
  f32x4 a = *(const f32x4*)(in + i);
  f32x4 b = *(const f32x4*)(in + i + 4);
  ushort8 o;
  o[0] = f2bf(a[0]); o[1] = f2bf(a[1]); o[2] = f2bf(a[2]); o[3] = f2bf(a[3]);
  o[4] = f2bf(b[0]); o[5] = f2bf(b[1]); o[6] = f2bf(b[2]); o[7] = f2bf(b[3]);
  *(ushort8*)(out + i) = o;
}

// ---------------- RoPE cos/sin table (fp64 for exactness) ----------------
__global__ void k_rope_table(const int* __restrict__ pos, float* __restrict__ tab) {
  int idx = blockIdx.x * blockDim.x + threadIdx.x;
  if (idx >= SEQ * HALF) return;
  int s = idx >> 6, d = idx & 63;
  double invf = pow(10000.0, -(double)d / 64.0);
  double ang = (double)pos[s] * invf;
  tab[idx * 2]     = (float)cos(ang);
  tab[idx * 2 + 1] = (float)sin(ang);
}

// ---------------- RoPE apply (in-place on bf16, optional 1/sqrt(D) fold) ----------------
__global__ void k_rope(u16* __restrict__ X, const float* __restrict__ tab, float scale) {
  int idx = blockIdx.x * blockDim.x + threadIdx.x;   // SEQ*NH*HALF
  if (idx >= SEQ * NH * HALF) return;
  int d = idx & 63;
  int h = (idx >> 6) & 31;
  int s = idx >> 11;
  u16* p = X + (size_t)s * EMB + h * HD + d;
  float x1 = bf2f(p[0]), x2 = bf2f(p[HALF]);
  float c  = tab[(s * HALF + d) * 2];
  float sn = tab[(s * HALF + d) * 2 + 1];
  p[0]    = f2bf((x1 * c - x2 * sn) * scale);
  p[HALF] = f2bf((x2 * c + x1 * sn) * scale);
}

// ---------------- bf16 MFMA GEMM, 2-phase double-buffered (T3-min), templated ----------------
// C = A[M][K] * W[N][K]^T + bias. WMxWN waves (64x64 per-wave MFMA sub-tile except wo);
// BK=32; linear LDS; global_load_lds w=16; stage(t+1) issued before compute(t).
// 1D grid, XCD-compact mapping: xcd = wg&7 owns bx in [xcd*NBX/8, ...+NBX/8).
// mode: 0 = bf16 [M][Nn], 1 = f32 [M][Nn], 2 = bf16 transposed [n][M],
//       3 = QKV fused (N=12288; seg by n0>>12: 0->C0 bf16, 1->C1 bf16, 2->C2 V^T)
template<int TBM, int TBN, int WM, int WN>
__global__ __launch_bounds__(WM * WN * 64) void k_gemm(
    const u16* __restrict__ A, const u16* __restrict__ W,
    const float* __restrict__ b0, const float* __restrict__ b1, const float* __restrict__ b2,
    void* __restrict__ C0, void* __restrict__ C1, void* __restrict__ C2,
    int M, int N, int K, int mode)
{
  constexpr int CH_A = TBM / 16, CH_B = TBN / 16;
  constexpr int CH_W = (CH_A + CH_B) / (WM * WN);   // staging chunks per wave
  constexpr int MA = TBM / WM / 16, NB = TBN / WN / 16;
  __shared__ alignas(16) u16 As[2][TBM * 32];
  __shared__ alignas(16) u16 Bs[2][TBN * 32];
  int tid = threadIdx.x;
  int lane = tid & 63, wid = tid >> 6;
  int wm = wid / WN, wn = wid % WN;
  int l15 = lane & 15, lhi = lane >> 4;

  // XCD-compact bijective mapping (requires NBX % 8 == 0)
  int NBY = M / TBM, NBX = N / TBN;
  int wg = blockIdx.x;
  int xcd = wg & 7, s = wg >> 3;
  int by = s % NBY, bxl = s / NBY;
  int bx = xcd * (NBX >> 3) + bxl;
  int m0 = by * TBM, n0 = bx * TBN;

  f32x4 acc[MA][NB] = {};

  int srow = lane >> 2;            // 0..15 within chunk
  int scol = (lane & 3) * 8;       // 0,8,16,24

  auto stage = [&](int buf, int k0) {
#pragma unroll
    for (int i = 0; i < CH_W; i++) {
      int chunk = wid * CH_W + i;
      if (chunk < CH_A) {
        int row = chunk * 16 + srow;
        GLL16(A + (size_t)(m0 + row) * K + k0 + scol, &As[buf][chunk * 512]);
      } else {
        int c2 = chunk - CH_A;
        int row = c2 * 16 + srow;
        GLL16(W + (size_t)(n0 + row) * K + k0 + scol, &Bs[buf][c2 * 512]);
      }
    }
  };

  int KT = K / 32;
  stage(0, 0);
  for (int t = 0; t < KT; t++) {
    __syncthreads();                       // drains stage(t) (vmcnt 0 at barrier)
    if (t + 1 < KT) stage((t + 1) & 1, (t + 1) * 32);   // lands during compute(t)

    const u16* as = As[t & 1];
    const u16* bs = Bs[t & 1];
    bf16x8 af[MA], bfr[NB];
#pragma unroll
    for (int a = 0; a < MA; a++)
      af[a] = *(const bf16x8*)&as[(wm * (TBM / WM) + a * 16 + l15) * 32 + lhi * 8];
#pragma unroll
    for (int b = 0; b < NB; b++)
      bfr[b] = *(const bf16x8*)&bs[(wn * (TBN / WN) + b * 16 + l15) * 32 + lhi * 8];
#pragma unroll
    for (int a = 0; a < MA; a++)
#pragma unroll
      for (int b = 0; b < NB; b++)
        acc[a][b] = __builtin_amdgcn_mfma_f32_16x16x32_bf16(af[a], bfr[b], acc[a][b], 0, 0, 0);
  }

  // epilogue: resolve output segment
  const float* bias = b0;
  void* Cout = C0;
  int mode_l = mode, Nn = N, n_base = n0;
  if (mode == 3) {
    int seg = n0 >> 12;
    Nn = EMB; n_base = n0 & 4095;
    if (seg == 0)      { bias = b0; Cout = C0; mode_l = 0; }
    else if (seg == 1) { bias = b1; Cout = C1; mode_l = 0; }
    else               { bias = b2; Cout = C2; mode_l = 2; }
  }

#pragma unroll
  for (int a = 0; a < MA; a++) {
    int m = m0 + wm * (TBM / WM) + a * 16 + lhi * 4;
#pragma unroll
    for (int b = 0; b < NB; b++) {
      int n = n_base + wn * (TBN / WN) + b * 16 + l15;
      float bs2 = bias[n];
      if (mode_l == 2) {
        u16x4 pk;
#pragma unroll
        for (int r = 0; r < 4; r++) pk[r] = f2bf(acc[a][b][r] + bs2);
        *(u16x4*)&((u16*)Cout)[(size_t)n * M + m] = pk;
      } else if (mode_l == 1) {
#pragma unroll
        for (int r = 0; r < 4; r++)
          ((float*)Cout)[(size_t)(m + r) * Nn + n] = acc[a][b][r] + bs2;
      } else {
#pragma unroll
        for (int r = 0; r < 4; r++)
          ((u16*)Cout)[(size_t)(m + r) * Nn + n] = f2bf(acc[a][b][r] + bs2);
      }
    }
  }
}

// ---------------- Flash attention (causal), bf16 MFMA, fp32 softmax ----------------
// QB=64 (4 waves x 16 rows), KVB=64. Paired q-blocks (qb, 31-qb): uniform 33 tiles/block.
// K and V^T staged via global_load_lds into double-buffered LDS with block-rotated layouts.
constexpr int QB = 64, KVB = 64;

__global__ __launch_bounds__(256) void k_flash(
    const u16* __restrict__ Q, const u16* __restrict__ K, const u16* __restrict__ VT,
    u16* __restrict__ ctx)
{
  __shared__ alignas(16) u16 Ks[2][KVB * 128];
  __shared__ alignas(16) u16 Vt[2][HD * 64];
  __shared__ alignas(16) u16 Pl[4][16 * 64];

  int tid = threadIdx.x, lane = tid & 63, wid = tid >> 6;
  int l15 = lane & 15, lhi = lane >> 4;
  int h = blockIdx.y;

  auto stage = [&](int buf, int t2) {
    int kv = t2 * KVB;
#pragma unroll
    for (int it = 0; it < 4; it++) {
      int chunk = tid + it * 256;          // 0..1023
      int r = chunk >> 4, bp = chunk & 15;
      GLL16(K + (size_t)(kv + r) * EMB + h * HD + (((bp - r) & 15) << 3), &Ks[buf][chunk * 8]);
    }
#pragma unroll
    for (int it = 0; it < 4; it++) {
      int chunk = tid + it * 256;
      int d = chunk >> 3, bp = chunk & 7;
      GLL16(VT + (size_t)(h * HD + d) * SEQ + kv + (((bp - d) & 7) << 3), &Vt[buf][chunk * 8]);
    }
  };

  for (int pi = 0; pi < 2; pi++) {
    int qb = pi ? (int)blockIdx.x : 31 - (int)blockIdx.x;
    int q0 = qb * QB;
    int qw = q0 + wid * 16;

    bf16x8 qf[4];
#pragma unroll
    for (int kc = 0; kc < 4; kc++)
      qf[kc] = *(const bf16x8*)&Q[(size_t)(qw + l15) * EMB + h * HD + kc * 32 + lhi * 8];

    f32x4 O[8] = {};
    float mrow[4], lrow[4];
#pragma unroll
    for (int r = 0; r < 4; r++) { mrow[r] = -3.0e38f; lrow[r] = 0.f; }

    int nt = qb + 1;
    __syncthreads();          // pass boundary: previous pass's LDS reads done
    stage(0, 0);
    for (int t = 0; t < nt; t++) {
      __syncthreads();        // drains stage(t) loads; prior compute done
      if (t + 1 < nt) stage((t + 1) & 1, t + 1);   // lands during compute(t)

      const u16* ks = Ks[t & 1];
      const u16* vt = Vt[t & 1];
      float p[4][4];
      bool need_mask = (t == nt - 1);   // only the diagonal tile needs masking
#pragma unroll
      for (int c = 0; c < 4; c++) {
        f32x4 s = {};
        int r0 = c * 16 + l15;
#pragma unroll
        for (int kc = 0; kc < 4; kc++) {
          bf16x8 kf = *(const bf16x8*)&ks[r0 * 128 + (((kc * 4 + lhi) + r0) & 15) * 8];
          s = __builtin_amdgcn_mfma_f32_16x16x32_bf16(qf[kc], kf, s, 0, 0, 0);
        }
#pragma unroll
        for (int r = 0; r < 4; r++) {
          float sv = s[r];
          if (need_mask) {
            int qg = qw + lhi * 4 + r;
            int kg = t * KVB + c * 16 + l15;
            if (kg > qg) sv = -3.0e38f;
          }
          p[c][r] = sv;
        }
      }
      float fscale[4];
#pragma unroll
      for (int r = 0; r < 4; r++) {
        float m = fmaxf(fmaxf(p[0][r], p[1][r]), fmaxf(p[2][r], p[3][r]));
#pragma unroll
        for (int x = 1; x < 16; x <<= 1) m = fmaxf(m, __shfl_xor(m, x, 64));
        float mnew = fmaxf(mrow[r], m);
        fscale[r] = __expf(mrow[r] - mnew);
        mrow[r] = mnew;
      }
#pragma unroll
      for (int c = 0; c < 4; c++)
#pragma unroll
        for (int r = 0; r < 4; r++)
          p[c][r] = __expf(p[c][r] - mrow[r]);
#pragma unroll
      for (int r = 0; r < 4; r++) {
        float s = p[0][r] + p[1][r] + p[2][r] + p[3][r];
#pragma unroll
        for (int x = 1; x < 16; x <<= 1) s += __shfl_xor(s, x, 64);
        lrow[r] = lrow[r] * fscale[r] + s;
      }
#pragma unroll
      for (int d = 0; d < 8; d++)
#pragma unroll
        for (int r = 0; r < 4; r++)
          O[d][r] *= fscale[r];
#pragma unroll
      for (int c = 0; c < 4; c++) {
        int kb = c * 2 + (l15 >> 3), klo = l15 & 7;
#pragma unroll
        for (int r = 0; r < 4; r++) {
          int q = lhi * 4 + r;
          Pl[wid][q * 64 + ((kb + (q >> 1)) & 7) * 8 + klo] = f2bf(p[c][r]);
        }
      }
#pragma unroll
      for (int ks2 = 0; ks2 < 2; ks2++) {
        int kb = ks2 * 4 + lhi;
        bf16x8 pf = *(const bf16x8*)&Pl[wid][l15 * 64 + ((kb + (l15 >> 1)) & 7) * 8];
#pragma unroll
        for (int ds = 0; ds < 8; ds++) {
          int d = ds * 16 + l15;
          bf16x8 vf = *(const bf16x8*)&vt[d * 64 + ((kb + d) & 7) * 8];
          O[ds] = __builtin_amdgcn_mfma_f32_16x16x32_bf16(pf, vf, O[ds], 0, 0, 0);
        }
      }
    }

#pragma unroll
    for (int r = 0; r < 4; r++) {
      float inv = 1.f / lrow[r];
      int qg = q0 + wid * 16 + lhi * 4 + r;
#pragma unroll
      for (int ds = 0; ds < 8; ds++)
        ctx[(size_t)qg * EMB + h * HD + ds * 16 + l15] = f2bf(O[ds][r] * inv);
    }
  }
}

// ---------------- launch ----------------
extern "C" void kernel_launch(void* const* d_in, const int* in_sizes, int n_in,
                              void* d_out, int out_size, void* d_ws, size_t ws_size,
                              hipStream_t stream) {
  const float* hs = (const float*)d_in[0];
  const float* wq = (const float*)d_in[1];
  const float* bq = (const float*)d_in[2];
  const float* wk = (const float*)d_in[3];
  const float* bk = (const float*)d_in[4];
  const float* wv = (const float*)d_in[5];
  const float* bv = (const float*)d_in[6];
  const float* wo = (const float*)d_in[7];
  const float* bo = (const float*)d_in[8];
  const int*  pos = (const int*)d_in[9];

  const size_t SE = (size_t)SEQ * EMB;   // 8M elems
  const size_t EE = (size_t)EMB * EMB;   // 16M elems
  const float qscale = 1.0f / 11.313708498984761f;  // 1/sqrt(128)

  char* ws = (char*)d_ws;
  size_t off = 0;
  auto alloc = [&](size_t b) { size_t o = off; off += (b + 255) & ~(size_t)255; return o; };

  size_t need_fused = ((SE * 2 + 255) & ~255ULL) + ((EE * 6 + 255) & ~255ULL) +
                      3 * ((SE * 2 + 255) & ~255ULL) + ((size_t)SEQ * HALF * 8 + 255);
  bool fused = ws_size >= need_fused + 4096;

  u16*  hsb = (u16*)(ws + alloc(SE * 2));
  u16*  wb  = (u16*)(ws + alloc(fused ? EE * 6 : EE * 2));  // fused: wq|wk|wv, reused for wo
  u16*  Qb  = (u16*)(ws + alloc(SE * 2));
  u16*  Kb  = (u16*)(ws + alloc(SE * 2));
  u16*  VTb = (u16*)(ws + alloc(SE * 2));                   // V^T, [E][S]
  float* tab = (float*)(ws + alloc((size_t)SEQ * HALF * 2 * 4));
  u16*  ctxb = hsb;   // hs dead after QKV GEMM; flash output reuses it

  dim3 cb(256);
  k_f32_to_bf16<<<dim3(SE / 2048), cb, 0, stream>>>(hs, hsb, (int)SE);
  k_rope_table<<<dim3(SEQ * HALF / 256), cb, 0, stream>>>(pos, tab);

  if (fused) {
    k_f32_to_bf16<<<dim3(EE / 2048), cb, 0, stream>>>(wq, wb, (int)EE);
    k_f32_to_bf16<<<dim3(EE / 2048), cb, 0, stream>>>(wk, wb + EE, (int)EE);
    k_f32_to_bf16<<<dim3(EE / 2048), cb, 0, stream>>>(wv, wb + 2 * EE, (int)EE);
    // fused QKV GEMM: 128x256 tile, 8 waves, N = 12288 -> grid 768 (3 blocks/CU)
    k_gemm<128, 256, 2, 4><<<dim3(768), dim3(512), 0, stream>>>(
        hsb, wb, bq, bk, bv, (void*)Qb, (void*)Kb, (void*)VTb, SEQ, 3 * EMB, EMB, 3);
  } else {
    k_f32_to_bf16<<<dim3(EE / 2048), cb, 0, stream>>>(wq, wb, (int)EE);
    k_gemm<128, 256, 2, 4><<<dim3(256), dim3(512), 0, stream>>>(
        hsb, wb, bq, bq, bq, (void*)Qb, nullptr, nullptr, SEQ, EMB, EMB, 0);
    k_f32_to_bf16<<<dim3(EE / 2048), cb, 0, stream>>>(wk, wb, (int)EE);
    k_gemm<128, 256, 2, 4><<<dim3(256), dim3(512), 0, stream>>>(
        hsb, wb, bk, bk, bk, (void*)Kb, nullptr, nullptr, SEQ, EMB, EMB, 0);
    k_f32_to_bf16<<<dim3(EE / 2048), cb, 0, stream>>>(wv, wb, (int)EE);
    k_gemm<128, 256, 2, 4><<<dim3(256), dim3(512), 0, stream>>>(
        hsb, wb, bv, bv, bv, (void*)VTb, nullptr, nullptr, SEQ, EMB, EMB, 2);
  }

  k_rope<<<dim3(SEQ * NH * HALF / 256), cb, 0, stream>>>(Qb, tab, qscale);
  k_rope<<<dim3(SEQ * NH * HALF / 256), cb, 0, stream>>>(Kb, tab, 1.0f);

  // attention (paired q-blocks: grid.x = 16)
  k_flash<<<dim3(16, NH), cb, 0, stream>>>(Qb, Kb, VTb, ctxb);

  // output projection: 64x128 tile, 2x2 waves -> grid 1024 (4 blocks/CU), f32 out
  k_f32_to_bf16<<<dim3(EE / 2048), cb, 0, stream>>>(wo, wb, (int)EE);
  k_gemm<64, 128, 2, 2><<<dim3(1024), cb, 0, stream>>>(
      ctxb, wb, bo, bo, bo, d_out, nullptr, nullptr, SEQ, EMB, EMB, 1);
}